// Round 1
// baseline (162.457 us; speedup 1.0000x reference)
//
#include <hip/hip_runtime.h>
#include <hip/hip_bf16.h>
#include <math.h>

typedef __attribute__((ext_vector_type(8))) short short8;
typedef __attribute__((ext_vector_type(4))) float f32x4;
typedef __attribute__((ext_vector_type(4))) int int4x;

#define BB 8
#define SS 2048
#define DD 768
#define HDIM 64
#define MM (BB*SS)   // 16384 total rows

// round-to-nearest-even fp32 -> bf16 bits
__device__ __forceinline__ short f2bf(float f) {
    union { float f; unsigned u; } v; v.f = f;
    unsigned r = (v.u + 0x7fffu + ((v.u >> 16) & 1u)) >> 16;
    return (short)r;
}

// ---------------- kernel 1: W -> Wt bf16, transposed: Wt[m*64+c][k] = W_m[k][c]
__global__ void prep_w(const float* __restrict__ Wq, const float* __restrict__ Wk,
                       const float* __restrict__ Wv, short* __restrict__ Wt) {
    int idx = blockIdx.x * 256 + threadIdx.x;      // 0 .. 192*768-1
    int col = idx / DD;                            // 0..191 (Q|K|V cols)
    int k   = idx - col * DD;
    const float* W = (col < 64) ? Wq : (col < 128) ? Wk : Wv;
    int c = col & 63;
    Wt[idx] = f2bf(W[k * HDIM + c]);
}

// ---------------- kernel 2: QKV projection, bf16 MFMA, X read once from HBM.
// Block: 128 thr (2 waves), 64 rows. Wave: 32 rows x 192 cols.
// Outputs: Qg,Kg [16384][64] bf16 row-major; Vt [64][16384] bf16 (V transposed).
__global__ __launch_bounds__(128)
void proj_qkv(const float* __restrict__ X, const short* __restrict__ Wt,
              const float* __restrict__ bq, const float* __restrict__ bk,
              const float* __restrict__ bv,
              short* __restrict__ Qg, short* __restrict__ Kg, short* __restrict__ Vt) {
    __shared__ short Wl[192 * 40];   // [col 192][k 32] padded to 40 (bank-conflict-free)
    const int tid = threadIdx.x;
    const int w = tid >> 6, lane = tid & 63;
    const int lr = lane & 15, lg = lane >> 4;
    const int row0 = blockIdx.x * 64;

    f32x4 acc[2][12];
    for (int rt = 0; rt < 2; rt++)
        for (int c = 0; c < 12; c++) acc[rt][c] = (f32x4)0.0f;

    for (int kk = 0; kk < 24; kk++) {
        __syncthreads();                     // protect Wl from prior-iter readers
        for (int i = tid; i < 768; i += 128) {
            int r = i >> 2, seg = i & 3;     // r: 0..191 col, seg: 16B chunk of 32 k's
            int4x v = *(const int4x*)(Wt + r * DD + kk * 32 + seg * 8);
            *(int4x*)(Wl + r * 40 + seg * 8) = v;
        }
        __syncthreads();

        short8 af[2];
        for (int rt = 0; rt < 2; rt++) {
            const float* xp = X + (size_t)(row0 + w * 32 + rt * 16 + lr) * DD + kk * 32 + lg * 8;
            f32x4 x0 = *(const f32x4*)xp;
            f32x4 x1 = *(const f32x4*)(xp + 4);
            short8 a;
            a[0]=f2bf(x0[0]); a[1]=f2bf(x0[1]); a[2]=f2bf(x0[2]); a[3]=f2bf(x0[3]);
            a[4]=f2bf(x1[0]); a[5]=f2bf(x1[1]); a[6]=f2bf(x1[2]); a[7]=f2bf(x1[3]);
            af[rt] = a;
        }
        for (int c = 0; c < 12; c++) {
            short8 bfr = *(const short8*)(Wl + (c * 16 + lr) * 40 + lg * 8);
            acc[0][c] = __builtin_amdgcn_mfma_f32_16x16x32_bf16(af[0], bfr, acc[0][c], 0, 0, 0);
            acc[1][c] = __builtin_amdgcn_mfma_f32_16x16x32_bf16(af[1], bfr, acc[1][c], 0, 0, 0);
        }
    }

    for (int rt = 0; rt < 2; rt++) {
        for (int c = 0; c < 12; c++) {
            int gcol = c * 16 + lr;
            int m = gcol >> 6, cc = gcol & 63;
            float bias = (m == 0 ? bq : m == 1 ? bk : bv)[cc];
            for (int i = 0; i < 4; i++) {
                int r = row0 + w * 32 + rt * 16 + lg * 4 + i;
                short o = f2bf(acc[rt][c][i] + bias);
                if (m == 0)      Qg[(size_t)r * HDIM + cc] = o;
                else if (m == 1) Kg[(size_t)r * HDIM + cc] = o;
                else             Vt[(size_t)cc * MM + r]   = o;
            }
        }
    }
}

// ---------------- kernel 3: causal flash attention, 4 waves/block, 16 q-rows/wave.
// K/V fragments straight from global (L2-resident); P via per-wave swizzled LDS.
__global__ __launch_bounds__(256)
void attn(const short* __restrict__ Qg, const short* __restrict__ Kg,
          const short* __restrict__ Vt, float* __restrict__ out) {
    __shared__ short Pl[4][16 * 64];   // per-wave P tile, XOR-swizzled
    const int tid = threadIdx.x;
    const int w = tid >> 6, lane = tid & 63;
    const int lr = lane & 15, lg = lane >> 4;
    const int qb = 31 - blockIdx.x;    // heavy blocks first
    const int b  = blockIdx.y;
    const int q0 = qb * 64 + w * 16;   // wave's q-row start
    const size_t qrow = (size_t)b * SS + q0;
    char* plbase = (char*)&Pl[w][0];

    short8 qf[2];
    qf[0] = *(const short8*)(Qg + (qrow + lr) * HDIM + lg * 8);
    qf[1] = *(const short8*)(Qg + (qrow + lr) * HDIM + 32 + lg * 8);

    f32x4 oacc[4];
    for (int d = 0; d < 4; d++) oacc[d] = (f32x4)0.0f;
    float mrow[4] = {-INFINITY, -INFINITY, -INFINITY, -INFINITY};
    float lrow[4] = {0.f, 0.f, 0.f, 0.f};
    const float scl = 0.03608439182435161f;   // 1/sqrt(768)

    for (int t = 0; t <= qb; t++) {
        const int kv0 = t * 64;
        f32x4 sacc[4];
        for (int c = 0; c < 4; c++) sacc[c] = (f32x4)0.0f;

        const short* kp = Kg + ((size_t)b * SS + kv0) * HDIM;
        for (int c = 0; c < 4; c++) {
            const short* kpc = kp + (size_t)(c * 16 + lr) * HDIM + lg * 8;
            short8 k0 = *(const short8*)(kpc);
            short8 k1 = *(const short8*)(kpc + 32);
            sacc[c] = __builtin_amdgcn_mfma_f32_16x16x32_bf16(qf[0], k0, sacc[c], 0, 0, 0);
            sacc[c] = __builtin_amdgcn_mfma_f32_16x16x32_bf16(qf[1], k1, sacc[c], 0, 0, 0);
        }

        const bool diag = (t == qb);
        float p[4][4];
        float rm[4] = {-1e30f, -1e30f, -1e30f, -1e30f};
        for (int c = 0; c < 4; c++) {
            for (int i = 0; i < 4; i++) {
                float s = sacc[c][i] * scl;
                if (diag) {
                    int kv = kv0 + c * 16 + lr;
                    int qr = q0 + lg * 4 + i;
                    if (kv > qr) s = -1e30f;
                }
                p[c][i] = s;
                rm[i] = fmaxf(rm[i], s);
            }
        }
        for (int i = 0; i < 4; i++) {
            float v = rm[i];
            v = fmaxf(v, __shfl_xor(v, 1));
            v = fmaxf(v, __shfl_xor(v, 2));
            v = fmaxf(v, __shfl_xor(v, 4));
            v = fmaxf(v, __shfl_xor(v, 8));
            rm[i] = v;
        }
        float rs[4];
        for (int i = 0; i < 4; i++) {
            float mn = fmaxf(mrow[i], rm[i]);
            float scale = __expf(mrow[i] - mn);   // exp(-inf)=0 on first tile
            mrow[i] = mn;
            lrow[i] *= scale;
            for (int d = 0; d < 4; d++) oacc[d][i] *= scale;
            float sum = 0.f;
            for (int c = 0; c < 4; c++) {
                float e = __expf(p[c][i] - mn);
                p[c][i] = e;
                sum += e;
            }
            rs[i] = sum;
        }
        for (int i = 0; i < 4; i++) {
            float v = rs[i];
            v += __shfl_xor(v, 1);
            v += __shfl_xor(v, 2);
            v += __shfl_xor(v, 4);
            v += __shfl_xor(v, 8);
            lrow[i] += v;
        }

        // P (C-layout regs) -> LDS bf16, XOR-swizzled rows
        for (int c = 0; c < 4; c++) {
            for (int i = 0; i < 4; i++) {
                int r = lg * 4 + i;
                int byteoff = r * 128 + (c * 16 + lr) * 2;
                *(short*)(plbase + (byteoff ^ ((r & 7) << 4))) = f2bf(p[c][i]);
            }
        }
        __syncthreads();   // all waves share same trip count (t<=qb)

        const short* vp = Vt + (size_t)b * SS + kv0;
        for (int ks = 0; ks < 2; ks++) {
            int byteoff = lr * 128 + ks * 64 + lg * 16;
            short8 pf = *(const short8*)(plbase + (byteoff ^ ((lr & 7) << 4)));
            for (int d = 0; d < 4; d++) {
                const short* vpc = vp + (size_t)(d * 16 + lr) * MM + ks * 32 + lg * 8;
                short8 vf = *(const short8*)vpc;
                oacc[d] = __builtin_amdgcn_mfma_f32_16x16x32_bf16(pf, vf, oacc[d], 0, 0, 0);
            }
        }
        __syncthreads();
    }

    for (int d = 0; d < 4; d++) {
        for (int i = 0; i < 4; i++) {
            int qr = q0 + lg * 4 + i;
            out[((size_t)b * SS + qr) * HDIM + d * 16 + lr] = oacc[d][i] / lrow[i];
        }
    }
}

extern "C" void kernel_launch(void* const* d_in, const int* in_sizes, int n_in,
                              void* d_out, int out_size, void* d_ws, size_t ws_size,
                              hipStream_t stream) {
    const float* X  = (const float*)d_in[0];
    const float* Wq = (const float*)d_in[1];
    const float* bq = (const float*)d_in[2];
    const float* Wk = (const float*)d_in[3];
    const float* bk = (const float*)d_in[4];
    const float* Wv = (const float*)d_in[5];
    const float* bv = (const float*)d_in[6];
    float* out = (float*)d_out;

    char* ws = (char*)d_ws;
    short* Wt = (short*)(ws);                              // 192*768*2   = 294912 B
    short* Qg = (short*)(ws + 294912);                     // 16384*64*2  = 2 MB
    short* Kg = (short*)(ws + 294912 + 2097152);
    short* Vt = (short*)(ws + 294912 + 2 * 2097152);       // total ~6.3 MB

    prep_w<<<576, 256, 0, stream>>>(Wq, Wk, Wv, Wt);
    proj_qkv<<<256, 128, 0, stream>>>(X, Wt, bq, bk, bv, Qg, Kg, Vt);
    attn<<<dim3(32, 8), 256, 0, stream>>>(Qg, Kg, Vt, out);
}

// Round 2
// 122.961 us; speedup vs baseline: 1.3212x; 1.3212x over previous
//
#include <hip/hip_runtime.h>
#include <hip/hip_bf16.h>
#include <math.h>

typedef __attribute__((ext_vector_type(8))) short short8;
typedef __attribute__((ext_vector_type(4))) float f32x4;
typedef __attribute__((ext_vector_type(4))) int int4x;

#define BB 8
#define SS 2048
#define DD 768
#define HDIM 64
#define MM (BB*SS)   // 16384 total rows

// round-to-nearest-even fp32 -> bf16 bits
__device__ __forceinline__ short f2bf(float f) {
    union { float f; unsigned u; } v; v.f = f;
    unsigned r = (v.u + 0x7fffu + ((v.u >> 16) & 1u)) >> 16;
    return (short)r;
}

// ---------------- kernel 1: W -> Wt bf16, transposed: Wt[m*64+c][k] = W_m[k][c]
__global__ void prep_w(const float* __restrict__ Wq, const float* __restrict__ Wk,
                       const float* __restrict__ Wv, short* __restrict__ Wt) {
    int idx = blockIdx.x * 256 + threadIdx.x;      // 0 .. 192*768-1
    int col = idx / DD;                            // 0..191 (Q|K|V cols)
    int k   = idx - col * DD;
    const float* W = (col < 64) ? Wq : (col < 128) ? Wk : Wv;
    int c = col & 63;
    Wt[idx] = f2bf(W[k * HDIM + c]);
}

// ---------------- kernel 2: QKV projection. 16 rows/block, 2 waves (col-split).
// 1024 blocks x 128 thr -> 8 waves/CU. W fragments direct from global (L2-hot).
// Outputs: Qg,Kg [16384][64] bf16 row-major; Vt [64][16384] bf16 (V transposed).
__global__ __launch_bounds__(128)
void proj_qkv(const float* __restrict__ X, const short* __restrict__ Wt,
              const float* __restrict__ bq, const float* __restrict__ bk,
              const float* __restrict__ bv,
              short* __restrict__ Qg, short* __restrict__ Kg, short* __restrict__ Vt) {
    const int tid = threadIdx.x;
    const int w = tid >> 6, lane = tid & 63;
    const int lr = lane & 15, lg = lane >> 4;
    const int row0 = blockIdx.x * 16;
    const int c0 = w * 6;                 // wave's first col-tile (of 12)

    f32x4 acc[6];
    for (int c = 0; c < 6; c++) acc[c] = (f32x4)0.0f;

    for (int kk = 0; kk < 24; kk++) {
        const float* xp = X + (size_t)(row0 + lr) * DD + kk * 32 + lg * 8;
        f32x4 x0 = *(const f32x4*)xp;
        f32x4 x1 = *(const f32x4*)(xp + 4);
        short8 a;
        a[0]=f2bf(x0[0]); a[1]=f2bf(x0[1]); a[2]=f2bf(x0[2]); a[3]=f2bf(x0[3]);
        a[4]=f2bf(x1[0]); a[5]=f2bf(x1[1]); a[6]=f2bf(x1[2]); a[7]=f2bf(x1[3]);
        for (int c = 0; c < 6; c++) {
            short8 bfr = *(const short8*)(Wt + (size_t)((c0 + c) * 16 + lr) * DD + kk * 32 + lg * 8);
            acc[c] = __builtin_amdgcn_mfma_f32_16x16x32_bf16(a, bfr, acc[c], 0, 0, 0);
        }
    }

    for (int c = 0; c < 6; c++) {
        int gcol = (c0 + c) * 16 + lr;
        int m = gcol >> 6, cc = gcol & 63;
        float bias = (m == 0 ? bq : m == 1 ? bk : bv)[cc];
        for (int i = 0; i < 4; i++) {
            int r = row0 + lg * 4 + i;
            short o = f2bf(acc[c][i] + bias);
            if (m == 0)      Qg[(size_t)r * HDIM + cc] = o;
            else if (m == 1) Kg[(size_t)r * HDIM + cc] = o;
            else             Vt[(size_t)cc * MM + r]   = o;
        }
    }
}

// ---------------- kernel 3: flash attention phase A (split-KV partials).
// Work item = (b, qtile j of 64 rows, kv chunk of <=8 64-row tiles).
// 80 chunks/batch * 8 batches = 640 blocks, 4 waves each (16 q-rows/wave).
__global__ __launch_bounds__(256)
void attn_part(const short* __restrict__ Qg, const short* __restrict__ Kg,
               const short* __restrict__ Vt,
               float* __restrict__ Opart, float* __restrict__ Ml) {
    __shared__ short Pl[4][16 * 64];   // per-wave P tile, XOR-swizzled
    const int tid = threadIdx.x;
    const int w = tid >> 6, lane = tid & 63;
    const int lr = lane & 15, lg = lane >> 4;
    const int b = blockIdx.y;

    // decode blockIdx.x in [0,80) -> (j, c): group g=j>>3 has g+1 chunks per j
    int idx = blockIdx.x;
    int g, rem;
    if      (idx <  8) { g = 0; rem = idx;      }
    else if (idx < 24) { g = 1; rem = idx - 8;  }
    else if (idx < 48) { g = 2; rem = idx - 24; }
    else               { g = 3; rem = idx - 48; }
    const int j = g * 8 + rem / (g + 1);
    const int c = rem - (rem / (g + 1)) * (g + 1);
    const int t0 = c * 8;
    const int t1 = min(j + 1, t0 + 8);

    const int q0 = j * 64 + w * 16;
    const size_t qrow = (size_t)b * SS + q0;
    char* plbase = (char*)&Pl[w][0];

    short8 qf[2];
    qf[0] = *(const short8*)(Qg + (qrow + lr) * HDIM + lg * 8);
    qf[1] = *(const short8*)(Qg + (qrow + lr) * HDIM + 32 + lg * 8);

    f32x4 oacc[4];
    for (int d = 0; d < 4; d++) oacc[d] = (f32x4)0.0f;
    float mrow[4] = {-INFINITY, -INFINITY, -INFINITY, -INFINITY};
    float lrow[4] = {0.f, 0.f, 0.f, 0.f};
    const float scl = 0.03608439182435161f;   // 1/sqrt(768)

    for (int t = t0; t < t1; t++) {
        const int kv0 = t * 64;
        f32x4 sacc[4];
        for (int ct = 0; ct < 4; ct++) sacc[ct] = (f32x4)0.0f;

        const short* kp = Kg + ((size_t)b * SS + kv0) * HDIM;
        for (int ct = 0; ct < 4; ct++) {
            const short* kpc = kp + (size_t)(ct * 16 + lr) * HDIM + lg * 8;
            short8 k0 = *(const short8*)(kpc);
            short8 k1 = *(const short8*)(kpc + 32);
            sacc[ct] = __builtin_amdgcn_mfma_f32_16x16x32_bf16(qf[0], k0, sacc[ct], 0, 0, 0);
            sacc[ct] = __builtin_amdgcn_mfma_f32_16x16x32_bf16(qf[1], k1, sacc[ct], 0, 0, 0);
        }

        const bool diag = (t == j);
        float p[4][4];
        float rm[4] = {-1e30f, -1e30f, -1e30f, -1e30f};
        for (int ct = 0; ct < 4; ct++) {
            for (int i = 0; i < 4; i++) {
                float s = sacc[ct][i] * scl;
                if (diag) {
                    int kv = kv0 + ct * 16 + lr;
                    int qr = q0 + lg * 4 + i;
                    if (kv > qr) s = -1e30f;
                }
                p[ct][i] = s;
                rm[i] = fmaxf(rm[i], s);
            }
        }
        for (int i = 0; i < 4; i++) {
            float v = rm[i];
            v = fmaxf(v, __shfl_xor(v, 1));
            v = fmaxf(v, __shfl_xor(v, 2));
            v = fmaxf(v, __shfl_xor(v, 4));
            v = fmaxf(v, __shfl_xor(v, 8));
            rm[i] = v;
        }
        float rs[4];
        for (int i = 0; i < 4; i++) {
            float mn = fmaxf(mrow[i], rm[i]);
            float scale = __expf(mrow[i] - mn);   // exp(-inf)=0 on first tile
            mrow[i] = mn;
            lrow[i] *= scale;
            for (int d = 0; d < 4; d++) oacc[d][i] *= scale;
            float sum = 0.f;
            for (int ct = 0; ct < 4; ct++) {
                float e = __expf(p[ct][i] - mn);
                p[ct][i] = e;
                sum += e;
            }
            rs[i] = sum;
        }
        for (int i = 0; i < 4; i++) {
            float v = rs[i];
            v += __shfl_xor(v, 1);
            v += __shfl_xor(v, 2);
            v += __shfl_xor(v, 4);
            v += __shfl_xor(v, 8);
            lrow[i] += v;
        }

        // P (C-layout regs) -> LDS bf16, XOR-swizzled rows
        for (int ct = 0; ct < 4; ct++) {
            for (int i = 0; i < 4; i++) {
                int r = lg * 4 + i;
                int byteoff = r * 128 + (ct * 16 + lr) * 2;
                *(short*)(plbase + (byteoff ^ ((r & 7) << 4))) = f2bf(p[ct][i]);
            }
        }
        __syncthreads();   // all waves share same [t0,t1)

        const short* vp = Vt + (size_t)b * SS + kv0;
        for (int ks = 0; ks < 2; ks++) {
            int byteoff = lr * 128 + ks * 64 + lg * 16;
            short8 pf = *(const short8*)(plbase + (byteoff ^ ((lr & 7) << 4)));
            for (int d = 0; d < 4; d++) {
                const short* vpc = vp + (size_t)(d * 16 + lr) * MM + ks * 32 + lg * 8;
                short8 vf = *(const short8*)vpc;
                oacc[d] = __builtin_amdgcn_mfma_f32_16x16x32_bf16(pf, vf, oacc[d], 0, 0, 0);
            }
        }
        __syncthreads();
    }

    // store partial (unnormalized O with local max mrow, plus m,l)
    const int pb = (b * 32 + j) * 4 + c;
    float* op = Opart + (size_t)pb * 4096 + (size_t)(w * 16) * 64;
    for (int d = 0; d < 4; d++)
        for (int i = 0; i < 4; i++)
            op[(lg * 4 + i) * 64 + d * 16 + lr] = oacc[d][i];
    if (lr == 0) {
        float* ml = Ml + (size_t)pb * 128;
        for (int i = 0; i < 4; i++) {
            ml[w * 16 + lg * 4 + i]      = mrow[i];
            ml[64 + w * 16 + lg * 4 + i] = lrow[i];
        }
    }
}

// ---------------- kernel 4: combine partials -> out
__global__ __launch_bounds__(256)
void attn_comb(const float* __restrict__ Opart, const float* __restrict__ Ml,
               float* __restrict__ out) {
    const int j = blockIdx.x, b = blockIdx.y;
    const int nc = (j >> 3) + 1;
    const int tid = threadIdx.x;
    const int r = tid >> 2, cq = tid & 3;
    const int base = (b * 32 + j) * 4;

    float m = -INFINITY;
    for (int c = 0; c < nc; c++) m = fmaxf(m, Ml[(size_t)(base + c) * 128 + r]);

    float L = 0.f;
    f32x4 acc[4];
    for (int q = 0; q < 4; q++) acc[q] = (f32x4)0.0f;
    for (int c = 0; c < nc; c++) {
        const float* ml = Ml + (size_t)(base + c) * 128;
        float sc = __expf(ml[r] - m);
        L += ml[64 + r] * sc;
        const float* op = Opart + (size_t)(base + c) * 4096 + r * 64 + cq * 16;
        for (int q = 0; q < 4; q++) {
            f32x4 v = *(const f32x4*)(op + q * 4);
            acc[q] += v * sc;
        }
    }
    float inv = 1.0f / L;
    float* o = out + ((size_t)b * SS + j * 64 + r) * HDIM + cq * 16;
    for (int q = 0; q < 4; q++) {
        f32x4 v = acc[q] * inv;
        *(f32x4*)(o + q * 4) = v;
    }
}

extern "C" void kernel_launch(void* const* d_in, const int* in_sizes, int n_in,
                              void* d_out, int out_size, void* d_ws, size_t ws_size,
                              hipStream_t stream) {
    const float* X  = (const float*)d_in[0];
    const float* Wq = (const float*)d_in[1];
    const float* bq = (const float*)d_in[2];
    const float* Wk = (const float*)d_in[3];
    const float* bk = (const float*)d_in[4];
    const float* Wv = (const float*)d_in[5];
    const float* bv = (const float*)d_in[6];
    float* out = (float*)d_out;

    char* ws = (char*)d_ws;
    short* Wt = (short*)(ws);                               // 294912 B
    short* Qg = (short*)(ws + 294912);                      // 2 MB
    short* Kg = (short*)(ws + 294912 + 2097152);            // 2 MB
    short* Vt = (short*)(ws + 294912 + 2 * 2097152);        // 2 MB
    float* Op = (float*)(ws + 294912 + 3 * 2097152);        // 16.8 MB
    float* Ml = (float*)(ws + 294912 + 3 * 2097152 + 16777216); // 512 KB

    prep_w<<<576, 256, 0, stream>>>(Wq, Wk, Wv, Wt);
    proj_qkv<<<1024, 128, 0, stream>>>(X, Wt, bq, bk, bv, Qg, Kg, Vt);
    attn_part<<<dim3(80, 8), 256, 0, stream>>>(Qg, Kg, Vt, Op, Ml);
    attn_comb<<<dim3(32, 8), 256, 0, stream>>>(Op, Ml, out);
}

// Round 3
// 104.042 us; speedup vs baseline: 1.5614x; 1.1818x over previous
//
#include <hip/hip_runtime.h>
#include <hip/hip_bf16.h>
#include <math.h>

typedef __attribute__((ext_vector_type(8))) short short8;
typedef __attribute__((ext_vector_type(4))) float f32x4;

#define BB 8
#define SS 2048
#define DD 768
#define HDIM 64
#define MM (BB*SS)   // 16384 total rows

// round-to-nearest-even fp32 -> bf16 bits
__device__ __forceinline__ short f2bf(float f) {
    union { float f; unsigned u; } v; v.f = f;
    unsigned r = (v.u + 0x7fffu + ((v.u >> 16) & 1u)) >> 16;
    return (short)r;
}

// ---------------- kernel 1: W -> Wt bf16, transposed: Wt[m*64+c][k] = W_m[k][c]
__global__ void prep_w(const float* __restrict__ Wq, const float* __restrict__ Wk,
                       const float* __restrict__ Wv, short* __restrict__ Wt) {
    int idx = blockIdx.x * 256 + threadIdx.x;      // 0 .. 192*768-1
    int col = idx / DD;                            // 0..191 (Q|K|V cols)
    int k   = idx - col * DD;
    const float* W = (col < 64) ? Wq : (col < 128) ? Wk : Wv;
    int c = col & 63;
    Wt[idx] = f2bf(W[k * HDIM + c]);
}

// ---------------- kernel 2: QKV projection. 16 rows/block, 4 waves K-split.
// Wave w reduces kk in [6w, 6w+6); all 12 col tiles per wave. LDS combine.
// 1024 blocks -> 16 waves/CU, serial chain 6 iters. X read once from HBM/L3.
__global__ __launch_bounds__(256, 4)
void proj_qkv(const float* __restrict__ X, const short* __restrict__ Wt,
              const float* __restrict__ bq, const float* __restrict__ bk,
              const float* __restrict__ bv,
              short* __restrict__ Qg, short* __restrict__ Kg, short* __restrict__ Vt) {
    __shared__ f32x4 red[3][12][64];   // 36 KB: partials from waves 1..3
    const int tid = threadIdx.x;
    const int w = tid >> 6, lane = tid & 63;
    const int lr = lane & 15, lg = lane >> 4;
    const int row0 = blockIdx.x * 16;

    f32x4 acc[12];
    #pragma unroll
    for (int c = 0; c < 12; c++) acc[c] = (f32x4)0.0f;

    #pragma unroll
    for (int kk2 = 0; kk2 < 6; kk2++) {
        const int kk = w * 6 + kk2;
        const float* xp = X + (size_t)(row0 + lr) * DD + kk * 32 + lg * 8;
        f32x4 x0 = *(const f32x4*)xp;
        f32x4 x1 = *(const f32x4*)(xp + 4);
        short8 a;
        a[0]=f2bf(x0[0]); a[1]=f2bf(x0[1]); a[2]=f2bf(x0[2]); a[3]=f2bf(x0[3]);
        a[4]=f2bf(x1[0]); a[5]=f2bf(x1[1]); a[6]=f2bf(x1[2]); a[7]=f2bf(x1[3]);
        #pragma unroll
        for (int c = 0; c < 12; c++) {
            short8 bfr = *(const short8*)(Wt + (size_t)(c * 16 + lr) * DD + kk * 32 + lg * 8);
            acc[c] = __builtin_amdgcn_mfma_f32_16x16x32_bf16(a, bfr, acc[c], 0, 0, 0);
        }
    }

    if (w > 0) {
        #pragma unroll
        for (int c = 0; c < 12; c++) red[w - 1][c][lane] = acc[c];
    }
    __syncthreads();
    if (w == 0) {
        #pragma unroll
        for (int c = 0; c < 12; c++) {
            acc[c] += red[0][c][lane] + red[1][c][lane] + red[2][c][lane];
            int m = c >> 2;                      // 0:Q 1:K 2:V
            int cc = (c & 3) * 16 + lr;          // col within the 64
            float bias = (m == 0 ? bq : m == 1 ? bk : bv)[cc];
            #pragma unroll
            for (int i = 0; i < 4; i++) {
                int r = row0 + lg * 4 + i;
                short o = f2bf(acc[c][i] + bias);
                if (m == 0)      Qg[(size_t)r * HDIM + cc] = o;
                else if (m == 1) Kg[(size_t)r * HDIM + cc] = o;
                else             Vt[(size_t)cc * MM + r]   = o;
            }
        }
    }
}

// ---------------- kernel 3: flash attention phase A (split-KV partials).
// Work item = (b, qtile j of 64 rows, kv chunk of <=C 64-row tiles).
// No __syncthreads: Pl is per-wave private; intra-wave LDS ordering is implicit.
__global__ __launch_bounds__(256)
void attn_part(const short* __restrict__ Qg, const short* __restrict__ Kg,
               const short* __restrict__ Vt,
               float* __restrict__ Opart, float* __restrict__ Ml,
               int C, int NP) {
    __shared__ short Pl[4][16 * 64];   // per-wave P tile, XOR-swizzled
    const int tid = threadIdx.x;
    const int w = tid >> 6, lane = tid & 63;
    const int lr = lane & 15, lg = lane >> 4;
    const int b = blockIdx.y;

    // decode blockIdx.x -> (j, c): group g = j/C has (g+1) chunks per j
    int idx = blockIdx.x;
    int g = 0;
    while (idx >= C * (g + 1) * (g + 2) / 2) g++;
    int rem = idx - C * g * (g + 1) / 2;
    int jq = rem / (g + 1);
    const int j = g * C + jq;
    const int c = rem - jq * (g + 1);
    const int t0 = c * C;
    const int t1 = min(j + 1, t0 + C);

    const int q0 = j * 64 + w * 16;
    const size_t qrow = (size_t)b * SS + q0;
    char* plbase = (char*)&Pl[w][0];

    short8 qf[2];
    qf[0] = *(const short8*)(Qg + (qrow + lr) * HDIM + lg * 8);
    qf[1] = *(const short8*)(Qg + (qrow + lr) * HDIM + 32 + lg * 8);

    f32x4 oacc[4];
    for (int d = 0; d < 4; d++) oacc[d] = (f32x4)0.0f;
    float mrow[4] = {-INFINITY, -INFINITY, -INFINITY, -INFINITY};
    float lrow[4] = {0.f, 0.f, 0.f, 0.f};
    const float scl = 0.03608439182435161f;   // 1/sqrt(768)

    for (int t = t0; t < t1; t++) {
        const int kv0 = t * 64;
        f32x4 sacc[4];
        for (int ct = 0; ct < 4; ct++) sacc[ct] = (f32x4)0.0f;

        const short* kp = Kg + ((size_t)b * SS + kv0) * HDIM;
        #pragma unroll
        for (int ct = 0; ct < 4; ct++) {
            const short* kpc = kp + (size_t)(ct * 16 + lr) * HDIM + lg * 8;
            short8 k0 = *(const short8*)(kpc);
            short8 k1 = *(const short8*)(kpc + 32);
            sacc[ct] = __builtin_amdgcn_mfma_f32_16x16x32_bf16(qf[0], k0, sacc[ct], 0, 0, 0);
            sacc[ct] = __builtin_amdgcn_mfma_f32_16x16x32_bf16(qf[1], k1, sacc[ct], 0, 0, 0);
        }

        const bool diag = (t == j);
        float p[4][4];
        float rm[4] = {-1e30f, -1e30f, -1e30f, -1e30f};
        #pragma unroll
        for (int ct = 0; ct < 4; ct++) {
            #pragma unroll
            for (int i = 0; i < 4; i++) {
                float s = sacc[ct][i] * scl;
                if (diag) {
                    int kv = kv0 + ct * 16 + lr;
                    int qr = q0 + lg * 4 + i;
                    if (kv > qr) s = -1e30f;
                }
                p[ct][i] = s;
                rm[i] = fmaxf(rm[i], s);
            }
        }
        #pragma unroll
        for (int i = 0; i < 4; i++) {
            float v = rm[i];
            v = fmaxf(v, __shfl_xor(v, 1));
            v = fmaxf(v, __shfl_xor(v, 2));
            v = fmaxf(v, __shfl_xor(v, 4));
            v = fmaxf(v, __shfl_xor(v, 8));
            rm[i] = v;
        }
        float rs[4];
        #pragma unroll
        for (int i = 0; i < 4; i++) {
            float mn = fmaxf(mrow[i], rm[i]);
            float scale = __expf(mrow[i] - mn);   // exp(-inf)=0 on first tile
            mrow[i] = mn;
            lrow[i] *= scale;
            for (int d = 0; d < 4; d++) oacc[d][i] *= scale;
            float sum = 0.f;
            #pragma unroll
            for (int ct = 0; ct < 4; ct++) {
                float e = __expf(p[ct][i] - mn);
                p[ct][i] = e;
                sum += e;
            }
            rs[i] = sum;
        }
        #pragma unroll
        for (int i = 0; i < 4; i++) {
            float v = rs[i];
            v += __shfl_xor(v, 1);
            v += __shfl_xor(v, 2);
            v += __shfl_xor(v, 4);
            v += __shfl_xor(v, 8);
            lrow[i] += v;
        }

        // P (C-layout regs) -> LDS bf16, XOR-swizzled rows (per-wave private)
        #pragma unroll
        for (int ct = 0; ct < 4; ct++) {
            #pragma unroll
            for (int i = 0; i < 4; i++) {
                int r = lg * 4 + i;
                int byteoff = r * 128 + (ct * 16 + lr) * 2;
                *(short*)(plbase + (byteoff ^ ((r & 7) << 4))) = f2bf(p[ct][i]);
            }
        }

        const short* vp = Vt + (size_t)b * SS + kv0;
        #pragma unroll
        for (int ks = 0; ks < 2; ks++) {
            int byteoff = lr * 128 + ks * 64 + lg * 16;
            short8 pf = *(const short8*)(plbase + (byteoff ^ ((lr & 7) << 4)));
            #pragma unroll
            for (int d = 0; d < 4; d++) {
                const short* vpc = vp + (size_t)(d * 16 + lr) * MM + ks * 32 + lg * 8;
                short8 vf = *(const short8*)vpc;
                oacc[d] = __builtin_amdgcn_mfma_f32_16x16x32_bf16(pf, vf, oacc[d], 0, 0, 0);
            }
        }
    }

    // store partial (unnormalized O with local max mrow, plus m,l)
    const int pb = (b * 32 + j) * NP + c;
    float* op = Opart + (size_t)pb * 4096 + (size_t)(w * 16) * 64;
    #pragma unroll
    for (int d = 0; d < 4; d++)
        #pragma unroll
        for (int i = 0; i < 4; i++)
            op[(lg * 4 + i) * 64 + d * 16 + lr] = oacc[d][i];
    if (lr == 0) {
        float* ml = Ml + (size_t)pb * 128;
        for (int i = 0; i < 4; i++) {
            ml[w * 16 + lg * 4 + i]      = mrow[i];
            ml[64 + w * 16 + lg * 4 + i] = lrow[i];
        }
    }
}

// ---------------- kernel 4: combine partials -> out
__global__ __launch_bounds__(256)
void attn_comb(const float* __restrict__ Opart, const float* __restrict__ Ml,
               float* __restrict__ out, int C, int NP) {
    const int j = blockIdx.x, b = blockIdx.y;
    const int nc = (j + C) / C;        // ceil((j+1)/C)
    const int tid = threadIdx.x;
    const int r = tid >> 2, cq = tid & 3;
    const int base = (b * 32 + j) * NP;

    float m = -INFINITY;
    for (int c = 0; c < nc; c++) m = fmaxf(m, Ml[(size_t)(base + c) * 128 + r]);

    float L = 0.f;
    f32x4 acc[4];
    for (int q = 0; q < 4; q++) acc[q] = (f32x4)0.0f;
    for (int c = 0; c < nc; c++) {
        const float* ml = Ml + (size_t)(base + c) * 128;
        float sc = __expf(ml[r] - m);
        L += ml[64 + r] * sc;
        const float* op = Opart + (size_t)(base + c) * 4096 + r * 64 + cq * 16;
        #pragma unroll
        for (int q = 0; q < 4; q++) {
            f32x4 v = *(const f32x4*)(op + q * 4);
            acc[q] += v * sc;
        }
    }
    float inv = 1.0f / L;
    float* o = out + ((size_t)b * SS + j * 64 + r) * HDIM + cq * 16;
    #pragma unroll
    for (int q = 0; q < 4; q++) {
        f32x4 v = acc[q] * inv;
        *(f32x4*)(o + q * 4) = v;
    }
}

extern "C" void kernel_launch(void* const* d_in, const int* in_sizes, int n_in,
                              void* d_out, int out_size, void* d_ws, size_t ws_size,
                              hipStream_t stream) {
    const float* X  = (const float*)d_in[0];
    const float* Wq = (const float*)d_in[1];
    const float* bq = (const float*)d_in[2];
    const float* Wk = (const float*)d_in[3];
    const float* bk = (const float*)d_in[4];
    const float* Wv = (const float*)d_in[5];
    const float* bv = (const float*)d_in[6];
    float* out = (float*)d_out;

    // chunk size: C=4 needs ~41.2 MB workspace; fall back to C=8 (~23.8 MB)
    const size_t baseOff = 294912 + 3 * 2097152;   // Wt + Qg + Kg + Vt
    size_t need4 = baseOff + (size_t)2048 * 4096 * 4 + (size_t)2048 * 128 * 4;
    int C, NP, gridx;
    if (ws_size >= need4) { C = 4; NP = 8; gridx = 144; }
    else                  { C = 8; NP = 4; gridx = 80;  }

    char* ws = (char*)d_ws;
    short* Wt = (short*)(ws);
    short* Qg = (short*)(ws + 294912);
    short* Kg = (short*)(ws + 294912 + 2097152);
    short* Vt = (short*)(ws + 294912 + 2 * 2097152);
    float* Op = (float*)(ws + baseOff);
    float* Ml = (float*)(ws + baseOff + (size_t)256 * 32 * NP * 4096 / 256 * 4); // = NP*1024*4096B... computed below instead

    // explicit, readable offset math:
    size_t opBytes = (size_t)8 * 32 * NP * 4096 * 4;   // partial O tiles
    Ml = (float*)(ws + baseOff + opBytes);

    prep_w<<<576, 256, 0, stream>>>(Wq, Wk, Wv, Wt);
    proj_qkv<<<1024, 256, 0, stream>>>(X, Wt, bq, bk, bv, Qg, Kg, Vt);
    attn_part<<<dim3(gridx, 8), 256, 0, stream>>>(Qg, Kg, Vt, Op, Ml, C, NP);
    attn_comb<<<dim3(32, 8), 256, 0, stream>>>(Op, Ml, out, C, NP);
}

// Round 4
// 62.364 us; speedup vs baseline: 2.6050x; 1.6683x over previous
//
#include <hip/hip_runtime.h>
#include <hip/hip_bf16.h>
#include <math.h>

typedef __attribute__((ext_vector_type(8))) short short8;
typedef __attribute__((ext_vector_type(4))) float f32x4;

#define SS 2048
#define DD 768
#define HDIM 64
#define MM 16384   // total rows = 8*2048

// round-to-nearest-even fp32 -> bf16 bits
__device__ __forceinline__ short f2bf(float f) {
    union { float f; unsigned u; } v; v.f = f;
    unsigned r = (v.u + 0x7fffu + ((v.u >> 16) & 1u)) >> 16;
    return (short)r;
}

// async global->LDS, 16B per lane; LDS dest = uniform base + lane*16,
// global src is per-lane (pre-swizzled for bank-conflict-free ds_read).
__device__ __forceinline__ void gl_lds(const void* g, void* l) {
    __builtin_amdgcn_global_load_lds(
        (const __attribute__((address_space(1))) unsigned*)g,
        (__attribute__((address_space(3))) unsigned*)l, 16, 0, 0);
}

// ---------------- kernel 1: W -> Wt bf16, transposed: Wt[m*64+c][k] = W_m[k][c]
__global__ void prep_w(const float* __restrict__ Wq, const float* __restrict__ Wk,
                       const float* __restrict__ Wv, short* __restrict__ Wt) {
    int idx = blockIdx.x * 256 + threadIdx.x;      // 0 .. 192*768-1
    int col = idx / DD;
    int k   = idx - col * DD;
    const float* W = (col < 64) ? Wq : (col < 128) ? Wk : Wv;
    int c = col & 63;
    Wt[idx] = f2bf(W[k * HDIM + c]);
}

// ---------------- kernel 2: QKV projection, m97-style staged GEMM.
// 512 blocks x 8 waves; tile 32 rows x 192 cols; BK=64 double-buffered.
// X (fp32) + Wt (bf16) staged via global_load_lds with swizzled source.
__global__ __launch_bounds__(512)
void proj_qkv(const float* __restrict__ X, const short* __restrict__ Wt,
              const float* __restrict__ bq, const float* __restrict__ bk,
              const float* __restrict__ bv,
              short* __restrict__ Qg, short* __restrict__ Kg, short* __restrict__ Vt) {
    __shared__ float Xl[2][2048];    // 8 KB per buf: [32 rows][64 k] fp32, swizzled
    __shared__ short Wl[2][12288];   // 24 KB per buf: [192 cols][64 k] bf16, swizzled
    const int tid = threadIdx.x;
    const int w = tid >> 6, lane = tid & 63;
    const int lr = lane & 15, lg = lane >> 4;
    const int wr = w >> 2, wc = w & 3;           // wave = 16 rows x 48 cols
    const int row0 = blockIdx.x * 32;

    f32x4 acc[3];
    #pragma unroll
    for (int cf = 0; cf < 3; cf++) acc[cf] = (f32x4)0.0f;

    // ---- staging (issue-early, drained by the loop-end __syncthreads) ----
    auto stage = [&](int kk, int buf) {
        {   // X slice: 8 instrs total, one per wave
            int o = w * 1024 + lane * 16;
            int row = o >> 8, ch = (o >> 4) & 15;
            const char* src = (const char*)X + (size_t)(row0 + row) * 3072
                              + kk * 256 + ((ch ^ (row & 7)) << 4);
            gl_lds(src, (char*)&Xl[buf][0] + w * 1024);
        }
        #pragma unroll
        for (int s = 0; s < 3; s++) {   // W slice: 24 instrs, 3 per wave
            int i = w * 3 + s;
            int o = i * 1024 + lane * 16;
            int col = o >> 7, ch = (o >> 4) & 7;
            const char* src = (const char*)Wt + (size_t)col * 1536
                              + kk * 128 + ((ch ^ (col & 7)) << 4);
            gl_lds(src, (char*)&Wl[buf][0] + i * 1024);
        }
    };

    stage(0, 0);
    __syncthreads();
    int buf = 0;
    for (int kk = 0; kk < 12; kk++) {
        if (kk < 11) stage(kk + 1, buf ^ 1);
        const char* xb = (const char*)&Xl[buf][0];
        const char* wb = (const char*)&Wl[buf][0];
        #pragma unroll
        for (int ksub = 0; ksub < 2; ksub++) {
            int r = wr * 16 + lr;
            int b0 = r * 256 + ksub * 128 + lg * 32;
            f32x4 x0 = *(const f32x4*)(xb + ((b0)      ^ ((r & 7) << 4)));
            f32x4 x1 = *(const f32x4*)(xb + ((b0 + 16) ^ ((r & 7) << 4)));
            short8 a;
            a[0]=f2bf(x0[0]); a[1]=f2bf(x0[1]); a[2]=f2bf(x0[2]); a[3]=f2bf(x0[3]);
            a[4]=f2bf(x1[0]); a[5]=f2bf(x1[1]); a[6]=f2bf(x1[2]); a[7]=f2bf(x1[3]);
            #pragma unroll
            for (int cf = 0; cf < 3; cf++) {
                int col = wc * 48 + cf * 16 + lr;
                short8 bfr = *(const short8*)(wb +
                    ((col * 128 + ksub * 64 + lg * 16) ^ ((col & 7) << 4)));
                acc[cf] = __builtin_amdgcn_mfma_f32_16x16x32_bf16(a, bfr, acc[cf], 0, 0, 0);
            }
        }
        __syncthreads();
        buf ^= 1;
    }

    #pragma unroll
    for (int cf = 0; cf < 3; cf++) {
        int gcol = wc * 48 + cf * 16 + lr;
        int m = gcol >> 6, cc = gcol & 63;
        float bias = (m == 0 ? bq : m == 1 ? bk : bv)[cc];
        #pragma unroll
        for (int i = 0; i < 4; i++) {
            int r = row0 + wr * 16 + lg * 4 + i;
            short o = f2bf(acc[cf][i] + bias);
            if (m == 0)      Qg[(size_t)r * HDIM + cc] = o;
            else if (m == 1) Kg[(size_t)r * HDIM + cc] = o;
            else             Vt[(size_t)cc * MM + r]   = o;
        }
    }
}

// ---------------- kernel 3: flash attention phase A, staged K/V, 8 waves.
// Block = (b, 128-row q-tile J, kv chunk of <=8 64-row tiles). 40 x 8 blocks.
__global__ __launch_bounds__(512)
void attn_part(const short* __restrict__ Qg, const short* __restrict__ Kg,
               const short* __restrict__ Vt,
               float* __restrict__ Opart, float* __restrict__ Ml) {
    __shared__ short Kl[2][4096];   // 8 KB per buf: [64 kv][64 d], swizzled
    __shared__ short Vl[2][4096];   // 8 KB per buf: [64 d][64 kv], swizzled
    __shared__ short Pl[8][1024];   // 2 KB per wave, swizzled
    const int tid = threadIdx.x;
    const int w = tid >> 6, lane = tid & 63;
    const int lr = lane & 15, lg = lane >> 4;
    const int b = blockIdx.y;

    // decode 39-bx -> (J, c): group g=J>>2 has g+1 chunks per J
    int idx = 39 - (int)blockIdx.x;   // heavy-first
    int g = 0;
    while (idx >= 2 * (g + 1) * (g + 2)) g++;
    int rem = idx - 2 * g * (g + 1);
    const int J = g * 4 + rem / (g + 1);
    const int c = rem - (rem / (g + 1)) * (g + 1);
    const int t0 = c * 8;
    const int t1 = min(2 * J + 2, t0 + 8);

    const int q0 = J * 128 + w * 16;
    char* plbase = (char*)&Pl[w][0];

    short8 qf[2];
    qf[0] = *(const short8*)(Qg + ((size_t)b * SS + q0 + lr) * HDIM + lg * 8);
    qf[1] = *(const short8*)(Qg + ((size_t)b * SS + q0 + lr) * HDIM + 32 + lg * 8);

    f32x4 oacc[4];
    #pragma unroll
    for (int d = 0; d < 4; d++) oacc[d] = (f32x4)0.0f;
    float mrow[4] = {-INFINITY, -INFINITY, -INFINITY, -INFINITY};
    float lrow[4] = {0.f, 0.f, 0.f, 0.f};
    const float scl = 0.03608439182435161f;   // 1/sqrt(768)

    auto stage = [&](int t, int buf) {
        const int kv0 = t * 64;
        {   // K tile: instr w of 8 (rows w*8..w*8+7)
            int o = w * 1024 + lane * 16;
            int row = o >> 7, ch = (o >> 4) & 7;
            const char* src = (const char*)Kg + ((size_t)b * SS + kv0) * 128
                              + row * 128 + ((ch ^ (row & 7)) << 4);
            gl_lds(src, (char*)&Kl[buf][0] + w * 1024);
        }
        {   // V tile: instr w of 8 (cols w*8..w*8+7)
            int o = w * 1024 + lane * 16;
            int col = o >> 7, ch = (o >> 4) & 7;
            const char* src = (const char*)Vt + (size_t)col * (MM * 2)
                              + ((size_t)b * SS + kv0) * 2 + ((ch ^ (col & 7)) << 4);
            gl_lds(src, (char*)&Vl[buf][0] + w * 1024);
        }
    };

    stage(t0, 0);
    __syncthreads();
    int buf = 0;
    for (int t = t0; t < t1; t++) {
        if (t + 1 < t1) stage(t + 1, buf ^ 1);
        const int kv0 = t * 64;
        const bool active = (kv0 <= q0 + 15);
        if (active) {
            const char* kb = (const char*)&Kl[buf][0];
            f32x4 sacc[4];
            #pragma unroll
            for (int ct = 0; ct < 4; ct++) sacc[ct] = (f32x4)0.0f;
            #pragma unroll
            for (int ct = 0; ct < 4; ct++) {
                int row = ct * 16 + lr;
                short8 k0 = *(const short8*)(kb + ((row * 128 +      lg * 16) ^ ((row & 7) << 4)));
                short8 k1 = *(const short8*)(kb + ((row * 128 + 64 + lg * 16) ^ ((row & 7) << 4)));
                sacc[ct] = __builtin_amdgcn_mfma_f32_16x16x32_bf16(qf[0], k0, sacc[ct], 0, 0, 0);
                sacc[ct] = __builtin_amdgcn_mfma_f32_16x16x32_bf16(qf[1], k1, sacc[ct], 0, 0, 0);
            }

            const bool maskt = (kv0 + 63 > q0);
            float p[4][4];
            float rm[4] = {-1e30f, -1e30f, -1e30f, -1e30f};
            #pragma unroll
            for (int ct = 0; ct < 4; ct++) {
                #pragma unroll
                for (int i = 0; i < 4; i++) {
                    float s = sacc[ct][i] * scl;
                    if (maskt) {
                        int kv = kv0 + ct * 16 + lr;
                        int qr = q0 + lg * 4 + i;
                        if (kv > qr) s = -1e30f;
                    }
                    p[ct][i] = s;
                    rm[i] = fmaxf(rm[i], s);
                }
            }
            #pragma unroll
            for (int i = 0; i < 4; i++) {
                float v = rm[i];
                v = fmaxf(v, __shfl_xor(v, 1));
                v = fmaxf(v, __shfl_xor(v, 2));
                v = fmaxf(v, __shfl_xor(v, 4));
                v = fmaxf(v, __shfl_xor(v, 8));
                rm[i] = v;
            }
            float rs[4];
            #pragma unroll
            for (int i = 0; i < 4; i++) {
                float mn = fmaxf(mrow[i], rm[i]);
                float scale = __expf(mrow[i] - mn);
                mrow[i] = mn;
                lrow[i] *= scale;
                for (int d = 0; d < 4; d++) oacc[d][i] *= scale;
                float sum = 0.f;
                #pragma unroll
                for (int ct = 0; ct < 4; ct++) {
                    float e = __expf(p[ct][i] - mn);
                    p[ct][i] = e;
                    sum += e;
                }
                rs[i] = sum;
            }
            #pragma unroll
            for (int i = 0; i < 4; i++) {
                float v = rs[i];
                v += __shfl_xor(v, 1);
                v += __shfl_xor(v, 2);
                v += __shfl_xor(v, 4);
                v += __shfl_xor(v, 8);
                lrow[i] += v;
            }

            // P (C-layout) -> per-wave LDS bf16, XOR-swizzled
            #pragma unroll
            for (int ct = 0; ct < 4; ct++) {
                #pragma unroll
                for (int i = 0; i < 4; i++) {
                    int r = lg * 4 + i;
                    int byteoff = r * 128 + (ct * 16 + lr) * 2;
                    *(short*)(plbase + (byteoff ^ ((r & 7) << 4))) = f2bf(p[ct][i]);
                }
            }

            const char* vb = (const char*)&Vl[buf][0];
            #pragma unroll
            for (int ks = 0; ks < 2; ks++) {
                int byteoff = lr * 128 + ks * 64 + lg * 16;
                short8 pf = *(const short8*)(plbase + (byteoff ^ ((lr & 7) << 4)));
                #pragma unroll
                for (int d = 0; d < 4; d++) {
                    int col = d * 16 + lr;
                    short8 vf = *(const short8*)(vb +
                        ((col * 128 + ks * 64 + lg * 16) ^ ((col & 7) << 4)));
                    oacc[d] = __builtin_amdgcn_mfma_f32_16x16x32_bf16(pf, vf, oacc[d], 0, 0, 0);
                }
            }
        }
        __syncthreads();
        buf ^= 1;
    }

    // store partial tile (128x64 fp32) + m,l
    const int pb = (b * 16 + J) * 4 + c;
    float* op = Opart + (size_t)pb * 8192 + (size_t)(w * 16) * 64;
    #pragma unroll
    for (int d = 0; d < 4; d++)
        #pragma unroll
        for (int i = 0; i < 4; i++)
            op[(lg * 4 + i) * 64 + d * 16 + lr] = oacc[d][i];
    if (lr == 0) {
        float* ml = Ml + (size_t)pb * 256;
        for (int i = 0; i < 4; i++) {
            ml[w * 16 + lg * 4 + i]       = mrow[i];
            ml[128 + w * 16 + lg * 4 + i] = lrow[i];
        }
    }
}

// ---------------- kernel 4: combine partials -> out
__global__ __launch_bounds__(256)
void attn_comb(const float* __restrict__ Opart, const float* __restrict__ Ml,
               float* __restrict__ out) {
    const int J = blockIdx.x, b = blockIdx.y;
    const int nc = (2 * J + 2 + 7) >> 3;
    const int tid = threadIdx.x;
    const int r = tid >> 1, h = tid & 1;      // row 0..127, col-half
    const int base = (b * 16 + J) * 4;

    float m = -INFINITY;
    for (int c = 0; c < nc; c++) m = fmaxf(m, Ml[(size_t)(base + c) * 256 + r]);

    float L = 0.f;
    f32x4 acc[8];
    #pragma unroll
    for (int q = 0; q < 8; q++) acc[q] = (f32x4)0.0f;
    for (int c = 0; c < nc; c++) {
        const float* ml = Ml + (size_t)(base + c) * 256;
        float sc = __expf(ml[r] - m);
        L += ml[128 + r] * sc;
        const float* op = Opart + (size_t)(base + c) * 8192 + r * 64 + h * 32;
        #pragma unroll
        for (int q = 0; q < 8; q++)
            acc[q] += *(const f32x4*)(op + q * 4) * sc;
    }
    float inv = 1.0f / L;
    float* o = out + ((size_t)b * SS + J * 128 + r) * HDIM + h * 32;
    #pragma unroll
    for (int q = 0; q < 8; q++) {
        f32x4 v = acc[q] * inv;
        *(f32x4*)(o + q * 4) = v;
    }
}

extern "C" void kernel_launch(void* const* d_in, const int* in_sizes, int n_in,
                              void* d_out, int out_size, void* d_ws, size_t ws_size,
                              hipStream_t stream) {
    const float* X  = (const float*)d_in[0];
    const float* Wq = (const float*)d_in[1];
    const float* bq = (const float*)d_in[2];
    const float* Wk = (const float*)d_in[3];
    const float* bk = (const float*)d_in[4];
    const float* Wv = (const float*)d_in[5];
    const float* bv = (const float*)d_in[6];
    float* out = (float*)d_out;

    char* ws = (char*)d_ws;
    short* Wt = (short*)(ws);                               // 294912 B
    short* Qg = (short*)(ws + 294912);                      // 2 MB
    short* Kg = (short*)(ws + 294912 + 2097152);            // 2 MB
    short* Vt = (short*)(ws + 294912 + 2 * 2097152);        // 2 MB
    size_t opOff = 294912 + 3 * (size_t)2097152;
    float* Op = (float*)(ws + opOff);                       // 512*8192*4 = 16 MB
    float* Ml = (float*)(ws + opOff + (size_t)512 * 8192 * 4);  // 512 KB

    prep_w<<<576, 256, 0, stream>>>(Wq, Wk, Wv, Wt);
    proj_qkv<<<512, 512, 0, stream>>>(X, Wt, bq, bk, bv, Qg, Kg, Vt);
    attn_part<<<dim3(40, 8), 512, 0, stream>>>(Qg, Kg, Vt, Op, Ml);
    attn_comb<<<dim3(16, 8), 256, 0, stream>>>(Op, Ml, out);
}